// Round 6
// baseline (151.764 us; speedup 1.0000x reference)
//
#include <hip/hip_runtime.h>
#include <math.h>

#define N_NODES 4096
#define F_IN    512
#define F_OUT   64
#define ALPHA   0.2f
#define NPART   16

typedef _Float16 half8 __attribute__((ext_vector_type(8)));
typedef _Float16 half4 __attribute__((ext_vector_type(4)));
typedef float    floatx4 __attribute__((ext_vector_type(4)));

union H8U4 { half8 h; uint32_t u[4]; };

// ---------------- k_prep: WT[t][k] = f16(W[k][t])  (64 x 512) ----------------
__global__ __launch_bounds__(256) void k_prep(const float* __restrict__ W,
                                              _Float16* __restrict__ WT) {
    int idx = blockIdx.x * 256 + threadIdx.x;   // 32768 total
    int t = idx >> 9;
    int k = idx & 511;
    WT[idx] = (_Float16)W[k * F_OUT + t];
}

// ---------------- k_pack: adj (int32, 64MB) -> bitmask (2MB) via ballot ----------------
// wave per half-row: 8192 waves, grid 2048.  bit L of word c <-> col half*2048 + c*64 + L
__global__ __launch_bounds__(256) void k_pack(const int* __restrict__ adj,
                                              unsigned long long* __restrict__ adjb) {
    int tid  = threadIdx.x;
    int lane = tid & 63;
    int waveId = blockIdx.x * 4 + (tid >> 6);   // 0..8191
    int row  = waveId >> 1;
    int half = waveId & 1;
    const int* base = adj + (size_t)row * N_NODES + half * 2048 + lane;
    unsigned long long* dst = adjb + row * 64 + half * 32;
#pragma unroll 8
    for (int c = 0; c < 32; ++c) {
        int av = base[c * 64];
        unsigned long long mk = __ballot(av > 0);
        if (lane == 0) dst[c] = mk;
    }
}

// ---------------- k_hW: h = x@W via MFMA (K-split across 4 waves); h, hT(f16), e1 ----------------
__global__ __launch_bounds__(256) void k_hW(const float* __restrict__ x,
                                            const _Float16* __restrict__ WT,
                                            const float* __restrict__ a,
                                            float* __restrict__ h,
                                            _Float16* __restrict__ hT,
                                            float* __restrict__ e1) {
    __shared__ float red[4][16][64];   // [wave][g4*4+r][lane]
    int tid  = threadIdx.x;
    int lane = tid & 63;
    int w    = tid >> 6;
    int i0   = blockIdx.x * 16;
    int n    = lane & 15;
    int quad = lane >> 4;

    floatx4 acc[4] = {{0,0,0,0},{0,0,0,0},{0,0,0,0},{0,0,0,0}};

    const float* xr = x + (size_t)(i0 + n) * F_IN + w * 128 + quad * 8;
    const _Float16* wb = WT + w * 128 + quad * 8;
#pragma unroll
    for (int kk = 0; kk < 128; kk += 32) {
        float4 x0 = *(const float4*)(xr + kk);
        float4 x1 = *(const float4*)(xr + kk + 4);
        half8 af = {(_Float16)x0.x, (_Float16)x0.y, (_Float16)x0.z, (_Float16)x0.w,
                    (_Float16)x1.x, (_Float16)x1.y, (_Float16)x1.z, (_Float16)x1.w};
#pragma unroll
        for (int g = 0; g < 4; ++g) {
            half8 bf = *(const half8*)(wb + (size_t)(g * 16 + n) * F_IN + kk);
            acc[g] = __builtin_amdgcn_mfma_f32_16x16x32_f16(af, bf, acc[g], 0, 0, 0);
        }
    }
#pragma unroll
    for (int g = 0; g < 4; ++g)
#pragma unroll
        for (int r = 0; r < 4; ++r)
            red[w][g * 4 + r][lane] = acc[g][r];
    __syncthreads();
    if (w != 0) return;
#pragma unroll
    for (int g = 0; g < 4; ++g)
#pragma unroll
        for (int r = 0; r < 4; ++r)
            acc[g][r] = red[0][g * 4 + r][lane] + red[1][g * 4 + r][lane] +
                        red[2][g * 4 + r][lane] + red[3][g * 4 + r][lane];
#pragma unroll
    for (int g = 0; g < 4; ++g) {
        half4 hv;
#pragma unroll
        for (int r = 0; r < 4; ++r) {
            h[(size_t)(i0 + quad * 4 + r) * F_OUT + g * 16 + n] = acc[g][r];
            hv[r] = (_Float16)acc[g][r];
        }
        *(half4*)(hT + (size_t)(g * 16 + n) * N_NODES + i0 + quad * 4) = hv;
    }
    float a1v[4];
#pragma unroll
    for (int g = 0; g < 4; ++g) a1v[g] = a[g * 16 + n];
#pragma unroll
    for (int r = 0; r < 4; ++r) {
        float v = acc[0][r] * a1v[0] + acc[1][r] * a1v[1] + acc[2][r] * a1v[2] + acc[3][r] * a1v[3];
        v += __shfl_xor(v, 1, 64);
        v += __shfl_xor(v, 2, 64);
        v += __shfl_xor(v, 4, 64);
        v += __shfl_xor(v, 8, 64);
        if (n == 0) e1[i0 + quad * 4 + r] = v;
    }
}

// ---------------- k_TqP: Tq (LDS) -> P[q][j] = f16(exp(lrelu(e1[j]+Tq[j&63]))) ----------------
__global__ __launch_bounds__(256) void k_TqP(const float* __restrict__ h,
                                             const float* __restrict__ a,
                                             const float* __restrict__ e1,
                                             _Float16* __restrict__ P) {
    __shared__ float part[4][64];
    __shared__ float TqS[64];
    int q = blockIdx.x;
    int tid = threadIdx.x;
    int t = tid & 63;
    int rp = tid >> 6;
    const float* a2 = a + F_OUT;
    float s = 0.f;
#pragma unroll
    for (int rr = 0; rr < 16; ++rr) {
        int r = rp * 16 + rr;
        s += a2[r] * h[(size_t)(r * 64 + q) * F_OUT + t];
    }
    part[rp][t] = s;
    __syncthreads();
    if (tid < 64) TqS[tid] = part[0][tid] + part[1][tid] + part[2][tid] + part[3][tid];
    __syncthreads();
#pragma unroll
    for (int it = 0; it < 4; ++it) {
        int j = (it * 256 + tid) * 4;
        float4 ev = *(const float4*)(e1 + j);
        float4 tv = *(const float4*)(TqS + (j & 63));
        float e[4] = {ev.x + tv.x, ev.y + tv.y, ev.z + tv.z, ev.w + tv.w};
        half4 pv;
#pragma unroll
        for (int r = 0; r < 4; ++r) {
            float xx = e[r] > 0.f ? e[r] : ALPHA * e[r];
            pv[r] = (_Float16)__expf(xx);
        }
        *(half4*)(P + (size_t)q * N_NODES + j) = pv;
    }
}

// ---------------- k_main: bitmask-gated MFMA; adj info = 2 int4 loads per wave ----------------
// 4096 waves: block b: s = b&15 (256-col chunk), g = (b>>4)*4 + w (row-group). grid 1024.
__global__ __launch_bounds__(256, 4) void k_main(const unsigned int* __restrict__ adjb32,
                                                 const _Float16* __restrict__ P,
                                                 const _Float16* __restrict__ hT,
                                                 float* __restrict__ out_part,
                                                 float* __restrict__ den_part) {
    int tid  = threadIdx.x;
    int lane = tid & 63;
    int w    = tid >> 6;
    int b    = blockIdx.x;
    int s    = b & 15;
    int g    = (b >> 4) * 4 + w;
    int i0   = g * 16;
    int q    = i0 >> 6;
    int n    = lane & 15;
    int quad = lane >> 4;
    int jbase = s * 256 + quad * 8;

    // bitmask words for row i0+n, cols [s*256, s*256+256): dwords s*8 .. s*8+7
    const unsigned int* mrow = adjb32 + (size_t)(i0 + n) * (N_NODES / 32) + s * 8;
    uint4 m0 = *(const uint4*)(mrow);
    uint4 m1 = *(const uint4*)(mrow + 4);
    unsigned int m32[8] = {m0.x, m0.y, m0.z, m0.w, m1.x, m1.y, m1.z, m1.w};

    const _Float16* prow = P + (size_t)q * N_NODES + jbase;
    const _Float16* hrow = hT + (size_t)n * N_NODES + jbase;

    floatx4 acc[4] = {{0,0,0,0},{0,0,0,0},{0,0,0,0},{0,0,0,0}};
    floatx4 accd = {0, 0, 0, 0};
    _Float16 one_h = (n == 0) ? (_Float16)1.0f : (_Float16)0.0f;
    half8 ones_f = {one_h, one_h, one_h, one_h, one_h, one_h, one_h, one_h};

#pragma unroll
    for (int c = 0; c < 8; ++c) {
        int joff = c * 32;
        H8U4 pv, af;
        pv.h = *(const half8*)(prow + joff);
        unsigned int byte = (m32[c] >> (quad * 8)) & 0xFFu;
#pragma unroll
        for (int d = 0; d < 4; ++d) {
            unsigned int msk = (((byte >> (2 * d)) & 1u) ? 0x0000FFFFu : 0u) |
                               (((byte >> (2 * d + 1)) & 1u) ? 0xFFFF0000u : 0u);
            af.u[d] = pv.u[d] & msk;
        }
#pragma unroll
        for (int g4 = 0; g4 < 4; ++g4) {
            half8 bf = *(const half8*)(hrow + (size_t)g4 * 16 * N_NODES + joff);
            acc[g4] = __builtin_amdgcn_mfma_f32_16x16x32_f16(af.h, bf, acc[g4], 0, 0, 0);
        }
        accd = __builtin_amdgcn_mfma_f32_16x16x32_f16(af.h, ones_f, accd, 0, 0, 0);
    }
    // plain stores to this chunk's private partial
    float* op = out_part + ((size_t)s * N_NODES + i0) * F_OUT;
#pragma unroll
    for (int g4 = 0; g4 < 4; ++g4)
#pragma unroll
        for (int r = 0; r < 4; ++r)
            op[(quad * 4 + r) * F_OUT + g4 * 16 + n] = acc[g4][r];
    if (n == 0) {
#pragma unroll
        for (int r = 0; r < 4; ++r)
            den_part[s * N_NODES + i0 + quad * 4 + r] = accd[r];
    }
}

// ---------------- k_out: out = relu(sum_s out_part / sum_s den_part) + bias (float4) ----------------
__global__ __launch_bounds__(256) void k_out(const float* __restrict__ out_part,
                                             const float* __restrict__ den_part,
                                             const float* __restrict__ bias,
                                             float* __restrict__ out) {
    int idx4 = blockIdx.x * 256 + threadIdx.x;   // 65536 float4s
    int base = idx4 * 4;
    int i = base >> 6;
    int t = base & 63;
    float4 sacc = {0.f, 0.f, 0.f, 0.f};
    float dacc = 0.f;
#pragma unroll
    for (int p = 0; p < NPART; ++p) {
        float4 v = ((const float4*)(out_part + (size_t)p * N_NODES * F_OUT))[idx4];
        sacc.x += v.x; sacc.y += v.y; sacc.z += v.z; sacc.w += v.w;
        dacc += den_part[p * N_NODES + i];
    }
    float4 bv = *(const float4*)(bias + t);
    float4 o;
    o.x = fmaxf(sacc.x / dacc, 0.f) + bv.x;
    o.y = fmaxf(sacc.y / dacc, 0.f) + bv.y;
    o.z = fmaxf(sacc.z / dacc, 0.f) + bv.z;
    o.w = fmaxf(sacc.w / dacc, 0.f) + bv.w;
    ((float4*)out)[idx4] = o;
}

extern "C" void kernel_launch(void* const* d_in, const int* in_sizes, int n_in,
                              void* d_out, int out_size, void* d_ws, size_t ws_size,
                              hipStream_t stream) {
    const float* x    = (const float*)d_in[0];
    const int*   adj  = (const int*)d_in[1];
    const float* W    = (const float*)d_in[2];
    const float* a    = (const float*)d_in[3];
    const float* bias = (const float*)d_in[4];
    float* out = (float*)d_out;

    char* ws = (char*)d_ws;
    float*    h        = (float*)ws;                            // 1 MB
    _Float16* hT       = (_Float16*)(ws + 1024 * 1024);         // 512 KB
    float*    e1       = (float*)(ws + 1536 * 1024);            // 16 KB
    _Float16* P        = (_Float16*)(ws + 1552 * 1024);         // 512 KB
    _Float16* WT       = (_Float16*)(ws + 2064 * 1024);         // 64 KB
    float*    out_part = (float*)(ws + 2128 * 1024);            // 16 MB (NPART=16)
    float*    den_part = (float*)(ws + (2128 + 16384) * 1024);  // 256 KB
    unsigned long long* adjb = (unsigned long long*)(ws + (2128 + 16384 + 256) * 1024); // 2 MB

    k_prep<<<128, 256, 0, stream>>>(W, WT);
    k_pack<<<2048, 256, 0, stream>>>(adj, adjb);
    k_hW  <<<256, 256, 0, stream>>>(x, WT, a, h, hT, e1);
    k_TqP <<<64, 256, 0, stream>>>(h, a, e1, P);
    k_main<<<1024, 256, 0, stream>>>((const unsigned int*)adjb, P, hT, out_part, den_part);
    k_out <<<256, 256, 0, stream>>>(out_part, den_part, bias, out);
}

// Round 9
// 143.787 us; speedup vs baseline: 1.0555x; 1.0555x over previous
//
#include <hip/hip_runtime.h>
#include <math.h>

#define N_NODES 4096
#define F_IN    512
#define F_OUT   64
#define ALPHA   0.2f

typedef _Float16 half8 __attribute__((ext_vector_type(8)));
typedef _Float16 half4 __attribute__((ext_vector_type(4)));
typedef float    floatx4 __attribute__((ext_vector_type(4)));

union H8U4 { half8 h; uint32_t u[4]; };

// ---------------- k_prep: WT[t][k] = f16(W[k][t])  (64 x 512) ----------------
__global__ __launch_bounds__(256) void k_prep(const float* __restrict__ W,
                                              _Float16* __restrict__ WT) {
    int idx = blockIdx.x * 256 + threadIdx.x;   // 32768 total
    int t = idx >> 9;
    int k = idx & 511;
    WT[idx] = (_Float16)W[k * F_OUT + t];
}

// ---------------- k_hW: h = x@W via MFMA (K-split across 4 waves); h, hT(f16), e1 ----------------
__global__ __launch_bounds__(256) void k_hW(const float* __restrict__ x,
                                            const _Float16* __restrict__ WT,
                                            const float* __restrict__ a,
                                            float* __restrict__ h,
                                            _Float16* __restrict__ hT,
                                            float* __restrict__ e1) {
    __shared__ float red[4][16][64];   // [wave][g4*4+r][lane]
    int tid  = threadIdx.x;
    int lane = tid & 63;
    int w    = tid >> 6;
    int i0   = blockIdx.x * 16;
    int n    = lane & 15;
    int quad = lane >> 4;

    floatx4 acc[4] = {{0,0,0,0},{0,0,0,0},{0,0,0,0},{0,0,0,0}};

    const float* xr = x + (size_t)(i0 + n) * F_IN + w * 128 + quad * 8;
    const _Float16* wb = WT + w * 128 + quad * 8;
#pragma unroll
    for (int kk = 0; kk < 128; kk += 32) {
        float4 x0 = *(const float4*)(xr + kk);
        float4 x1 = *(const float4*)(xr + kk + 4);
        half8 af = {(_Float16)x0.x, (_Float16)x0.y, (_Float16)x0.z, (_Float16)x0.w,
                    (_Float16)x1.x, (_Float16)x1.y, (_Float16)x1.z, (_Float16)x1.w};
#pragma unroll
        for (int g = 0; g < 4; ++g) {
            half8 bf = *(const half8*)(wb + (size_t)(g * 16 + n) * F_IN + kk);
            acc[g] = __builtin_amdgcn_mfma_f32_16x16x32_f16(af, bf, acc[g], 0, 0, 0);
        }
    }
#pragma unroll
    for (int g = 0; g < 4; ++g)
#pragma unroll
        for (int r = 0; r < 4; ++r)
            red[w][g * 4 + r][lane] = acc[g][r];
    __syncthreads();
    if (w != 0) return;
#pragma unroll
    for (int g = 0; g < 4; ++g)
#pragma unroll
        for (int r = 0; r < 4; ++r)
            acc[g][r] = red[0][g * 4 + r][lane] + red[1][g * 4 + r][lane] +
                        red[2][g * 4 + r][lane] + red[3][g * 4 + r][lane];
#pragma unroll
    for (int g = 0; g < 4; ++g) {
        half4 hv;
#pragma unroll
        for (int r = 0; r < 4; ++r) {
            h[(size_t)(i0 + quad * 4 + r) * F_OUT + g * 16 + n] = acc[g][r];
            hv[r] = (_Float16)acc[g][r];
        }
        *(half4*)(hT + (size_t)(g * 16 + n) * N_NODES + i0 + quad * 4) = hv;
    }
    float a1v[4];
#pragma unroll
    for (int g = 0; g < 4; ++g) a1v[g] = a[g * 16 + n];
#pragma unroll
    for (int r = 0; r < 4; ++r) {
        float v = acc[0][r] * a1v[0] + acc[1][r] * a1v[1] + acc[2][r] * a1v[2] + acc[3][r] * a1v[3];
        v += __shfl_xor(v, 1, 64);
        v += __shfl_xor(v, 2, 64);
        v += __shfl_xor(v, 4, 64);
        v += __shfl_xor(v, 8, 64);
        if (n == 0) e1[i0 + quad * 4 + r] = v;
    }
}

// ---------------- k_TqP: 256 blocks: block = (q, j-quarter). Tq in LDS (x4 redundant), P slice ----
__global__ __launch_bounds__(256) void k_TqP(const float* __restrict__ h,
                                             const float* __restrict__ a,
                                             const float* __restrict__ e1,
                                             _Float16* __restrict__ P) {
    __shared__ float part[4][64];
    __shared__ float TqS[64];
    int b = blockIdx.x;
    int q = b >> 2;
    int quarter = b & 3;
    int tid = threadIdx.x;
    int t = tid & 63;
    int rp = tid >> 6;
    const float* a2 = a + F_OUT;
    float s = 0.f;
#pragma unroll
    for (int rr = 0; rr < 16; ++rr) {
        int r = rp * 16 + rr;
        s += a2[r] * h[(size_t)(r * 64 + q) * F_OUT + t];
    }
    part[rp][t] = s;
    __syncthreads();
    if (tid < 64) TqS[tid] = part[0][tid] + part[1][tid] + part[2][tid] + part[3][tid];
    __syncthreads();
    int j = quarter * 1024 + tid * 4;
    float4 ev = *(const float4*)(e1 + j);
    float4 tv = *(const float4*)(TqS + (j & 63));
    float e[4] = {ev.x + tv.x, ev.y + tv.y, ev.z + tv.z, ev.w + tv.w};
    half4 pv;
#pragma unroll
    for (int r = 0; r < 4; ++r) {
        float xx = e[r] > 0.f ? e[r] : ALPHA * e[r];
        pv[r] = (_Float16)__expf(xx);
    }
    *(half4*)(P + (size_t)q * N_NODES + j) = pv;
}

// ---------------- k_main: FUSED pack + MFMA + cross-wave reduce + epilogue ----------------
// 256 blocks x 256 thr. Block = 16 rows. Phase1: coalesced adj stream -> LDS bitmask (+P stage).
// Phase2: wave w MFMAs j-quarter [1024w,1024w+1024). Phase3: LDS reduce, relu(acc/den)+bias -> out.
#define MSTRIDE64 65   // u64 stride per row (=130 u32; bank stride 2 -> conflict-free)
#define RSTRIDE   65   // float stride per row in reduction buffer

__global__ __launch_bounds__(256) void k_main(const int* __restrict__ adj,
                                              const _Float16* __restrict__ P,
                                              const _Float16* __restrict__ hT,
                                              const float* __restrict__ bias,
                                              float* __restrict__ out) {
    __shared__ unsigned long long lds_mask[16 * MSTRIDE64];   // 8320 B
    __shared__ _Float16 lds_P[N_NODES];                       // 8 KB
    __shared__ float lds_red[4][16 * RSTRIDE];                // 16640 B
    __shared__ float lds_den[4][16];

    int tid  = threadIdx.x;
    int lane = tid & 63;
    int w    = tid >> 6;
    int i0   = blockIdx.x * 16;
    int q    = i0 >> 6;
    int n    = lane & 15;
    int quad = lane >> 4;

    // ---- phase 0: stage P[q][:] into LDS ----
    {
        const _Float16* Pq = P + (size_t)q * N_NODES;
        *(half8*)&lds_P[tid * 16]     = *(const half8*)(Pq + tid * 16);
        *(half8*)&lds_P[tid * 16 + 8] = *(const half8*)(Pq + tid * 16 + 8);
    }

    // ---- phase 1: stream adj rows coalesced, ballot into LDS bitmask ----
#pragma unroll
    for (int r = 0; r < 4; ++r) {
        int row = 4 * w + r;
        const int* rowp = adj + (size_t)(i0 + row) * N_NODES + lane;
#pragma unroll
        for (int bt = 0; bt < 4; ++bt) {
            int v[16];
#pragma unroll
            for (int u = 0; u < 16; ++u) v[u] = rowp[(bt * 16 + u) * 64];
#pragma unroll
            for (int u = 0; u < 16; ++u) {
                unsigned long long mk = __ballot(v[u] > 0);
                if (lane == 0) lds_mask[row * MSTRIDE64 + bt * 16 + u] = mk;
            }
        }
    }
    __syncthreads();

    // ---- phase 2: MFMA over j-quarter ----
    const unsigned int* m32 = (const unsigned int*)lds_mask;
    floatx4 acc[4] = {{0,0,0,0},{0,0,0,0},{0,0,0,0},{0,0,0,0}};
    floatx4 accd = {0, 0, 0, 0};
    _Float16 one_h = (n == 0) ? (_Float16)1.0f : (_Float16)0.0f;
    half8 ones_f = {one_h, one_h, one_h, one_h, one_h, one_h, one_h, one_h};
    const _Float16* hrow = hT + (size_t)n * N_NODES;
    int jw = w * 1024;

#pragma unroll 8
    for (int c = 0; c < 32; ++c) {
        int joff = jw + c * 32;
        unsigned int word = m32[n * (2 * MSTRIDE64) + (joff >> 5)];
        unsigned int byte = (word >> (quad * 8)) & 0xFFu;
        H8U4 pv, af;
        pv.h = *(const half8*)&lds_P[joff + quad * 8];
#pragma unroll
        for (int d = 0; d < 4; ++d) {
            unsigned int msk = (((byte >> (2 * d)) & 1u) ? 0x0000FFFFu : 0u) |
                               (((byte >> (2 * d + 1)) & 1u) ? 0xFFFF0000u : 0u);
            af.u[d] = pv.u[d] & msk;
        }
#pragma unroll
        for (int g4 = 0; g4 < 4; ++g4) {
            half8 bf = *(const half8*)(hrow + (size_t)g4 * 16 * N_NODES + joff + quad * 8);
            acc[g4] = __builtin_amdgcn_mfma_f32_16x16x32_f16(af.h, bf, acc[g4], 0, 0, 0);
        }
        accd = __builtin_amdgcn_mfma_f32_16x16x32_f16(af.h, ones_f, accd, 0, 0, 0);
    }

    // write per-wave partials to LDS  (C: row = quad*4+r, col = g4*16+n)
#pragma unroll
    for (int g4 = 0; g4 < 4; ++g4)
#pragma unroll
        for (int r = 0; r < 4; ++r)
            lds_red[w][(quad * 4 + r) * RSTRIDE + g4 * 16 + n] = acc[g4][r];
    if (n == 0) {
#pragma unroll
        for (int r = 0; r < 4; ++r)
            lds_den[w][quad * 4 + r] = accd[r];
    }
    __syncthreads();

    // ---- phase 3: reduce 4 waves, epilogue, final store ----
    {
        int row = tid >> 4;            // 0..15
        int col = (tid & 15) * 4;      // 0..60
        float v0 = 0.f, v1 = 0.f, v2 = 0.f, v3 = 0.f, d = 0.f;
#pragma unroll
        for (int ww = 0; ww < 4; ++ww) {
            const float* rp = &lds_red[ww][row * RSTRIDE + col];
            v0 += rp[0]; v1 += rp[1]; v2 += rp[2]; v3 += rp[3];
            d += lds_den[ww][row];
        }
        float4 bv = *(const float4*)(bias + col);
        float4 o;
        o.x = fmaxf(v0 / d, 0.f) + bv.x;
        o.y = fmaxf(v1 / d, 0.f) + bv.y;
        o.z = fmaxf(v2 / d, 0.f) + bv.z;
        o.w = fmaxf(v3 / d, 0.f) + bv.w;
        *(float4*)(out + (size_t)(i0 + row) * F_OUT + col) = o;
    }
}

extern "C" void kernel_launch(void* const* d_in, const int* in_sizes, int n_in,
                              void* d_out, int out_size, void* d_ws, size_t ws_size,
                              hipStream_t stream) {
    const float* x    = (const float*)d_in[0];
    const int*   adj  = (const int*)d_in[1];
    const float* W    = (const float*)d_in[2];
    const float* a    = (const float*)d_in[3];
    const float* bias = (const float*)d_in[4];
    float* out = (float*)d_out;

    char* ws = (char*)d_ws;
    float*    h  = (float*)ws;                            // 1 MB
    _Float16* hT = (_Float16*)(ws + 1024 * 1024);         // 512 KB
    float*    e1 = (float*)(ws + 1536 * 1024);            // 16 KB
    _Float16* P  = (_Float16*)(ws + 1552 * 1024);         // 512 KB
    _Float16* WT = (_Float16*)(ws + 2064 * 1024);         // 64 KB

    k_prep<<<128, 256, 0, stream>>>(W, WT);
    k_hW  <<<256, 256, 0, stream>>>(x, WT, a, h, hT, e1);
    k_TqP <<<256, 256, 0, stream>>>(h, a, e1, P);
    k_main<<<256, 256, 0, stream>>>(adj, P, hT, bias, out);
}

// Round 10
// 128.624 us; speedup vs baseline: 1.1799x; 1.1179x over previous
//
#include <hip/hip_runtime.h>
#include <math.h>

#define N_NODES 4096
#define F_IN    512
#define F_OUT   64
#define ALPHA   0.2f
#define NPART   32

typedef _Float16 half8 __attribute__((ext_vector_type(8)));
typedef _Float16 half4 __attribute__((ext_vector_type(4)));
typedef float    floatx4 __attribute__((ext_vector_type(4)));

union H8U4 { half8 h; uint32_t u[4]; };

// async global->LDS DMA, 16B per lane, dest = lds_base + lane*16 (wave-uniform base)
__device__ __forceinline__ void async_copy16(void* lds, const void* g) {
    __builtin_amdgcn_global_load_lds(
        (const __attribute__((address_space(1))) unsigned int*)g,
        (__attribute__((address_space(3))) unsigned int*)lds, 16, 0, 0);
}

// ---------------- k_prep: WT[t][k] = f16(W[k][t])  (64 x 512) ----------------
__global__ __launch_bounds__(256) void k_prep(const float* __restrict__ W,
                                              _Float16* __restrict__ WT) {
    int idx = blockIdx.x * 256 + threadIdx.x;   // 32768 total
    int t = idx >> 9;
    int k = idx & 511;
    WT[idx] = (_Float16)W[k * F_OUT + t];
}

// ---------------- k_hW: h = x@W via MFMA (K-split across 4 waves); h, hT(f16), e1 ----------------
__global__ __launch_bounds__(256) void k_hW(const float* __restrict__ x,
                                            const _Float16* __restrict__ WT,
                                            const float* __restrict__ a,
                                            float* __restrict__ h,
                                            _Float16* __restrict__ hT,
                                            float* __restrict__ e1) {
    __shared__ float red[4][16][64];   // [wave][g4*4+r][lane]
    int tid  = threadIdx.x;
    int lane = tid & 63;
    int w    = tid >> 6;
    int i0   = blockIdx.x * 16;
    int n    = lane & 15;
    int quad = lane >> 4;

    floatx4 acc[4] = {{0,0,0,0},{0,0,0,0},{0,0,0,0},{0,0,0,0}};

    const float* xr = x + (size_t)(i0 + n) * F_IN + w * 128 + quad * 8;
    const _Float16* wb = WT + w * 128 + quad * 8;
#pragma unroll
    for (int kk = 0; kk < 128; kk += 32) {
        float4 x0 = *(const float4*)(xr + kk);
        float4 x1 = *(const float4*)(xr + kk + 4);
        half8 af = {(_Float16)x0.x, (_Float16)x0.y, (_Float16)x0.z, (_Float16)x0.w,
                    (_Float16)x1.x, (_Float16)x1.y, (_Float16)x1.z, (_Float16)x1.w};
#pragma unroll
        for (int g = 0; g < 4; ++g) {
            half8 bf = *(const half8*)(wb + (size_t)(g * 16 + n) * F_IN + kk);
            acc[g] = __builtin_amdgcn_mfma_f32_16x16x32_f16(af, bf, acc[g], 0, 0, 0);
        }
    }
#pragma unroll
    for (int g = 0; g < 4; ++g)
#pragma unroll
        for (int r = 0; r < 4; ++r)
            red[w][g * 4 + r][lane] = acc[g][r];
    __syncthreads();
    if (w != 0) return;
#pragma unroll
    for (int g = 0; g < 4; ++g)
#pragma unroll
        for (int r = 0; r < 4; ++r)
            acc[g][r] = red[0][g * 4 + r][lane] + red[1][g * 4 + r][lane] +
                        red[2][g * 4 + r][lane] + red[3][g * 4 + r][lane];
#pragma unroll
    for (int g = 0; g < 4; ++g) {
        half4 hv;
#pragma unroll
        for (int r = 0; r < 4; ++r) {
            h[(size_t)(i0 + quad * 4 + r) * F_OUT + g * 16 + n] = acc[g][r];
            hv[r] = (_Float16)acc[g][r];
        }
        *(half4*)(hT + (size_t)(g * 16 + n) * N_NODES + i0 + quad * 4) = hv;
    }
    float a1v[4];
#pragma unroll
    for (int g = 0; g < 4; ++g) a1v[g] = a[g * 16 + n];
#pragma unroll
    for (int r = 0; r < 4; ++r) {
        float v = acc[0][r] * a1v[0] + acc[1][r] * a1v[1] + acc[2][r] * a1v[2] + acc[3][r] * a1v[3];
        v += __shfl_xor(v, 1, 64);
        v += __shfl_xor(v, 2, 64);
        v += __shfl_xor(v, 4, 64);
        v += __shfl_xor(v, 8, 64);
        if (n == 0) e1[i0 + quad * 4 + r] = v;
    }
}

// ---------------- k_TqP: 256 blocks: block = (q, j-quarter). Tq in LDS, P slice ----------------
__global__ __launch_bounds__(256) void k_TqP(const float* __restrict__ h,
                                             const float* __restrict__ a,
                                             const float* __restrict__ e1,
                                             _Float16* __restrict__ P) {
    __shared__ float part[4][64];
    __shared__ float TqS[64];
    int b = blockIdx.x;
    int q = b >> 2;
    int quarter = b & 3;
    int tid = threadIdx.x;
    int t = tid & 63;
    int rp = tid >> 6;
    const float* a2 = a + F_OUT;
    float s = 0.f;
#pragma unroll
    for (int rr = 0; rr < 16; ++rr) {
        int r = rp * 16 + rr;
        s += a2[r] * h[(size_t)(r * 64 + q) * F_OUT + t];
    }
    part[rp][t] = s;
    __syncthreads();
    if (tid < 64) TqS[tid] = part[0][tid] + part[1][tid] + part[2][tid] + part[3][tid];
    __syncthreads();
    int j = quarter * 1024 + tid * 4;
    float4 ev = *(const float4*)(e1 + j);
    float4 tv = *(const float4*)(TqS + (j & 63));
    float e[4] = {ev.x + tv.x, ev.y + tv.y, ev.z + tv.z, ev.w + tv.w};
    half4 pv;
#pragma unroll
    for (int r = 0; r < 4; ++r) {
        float xx = e[r] > 0.f ? e[r] : ALPHA * e[r];
        pv[r] = (_Float16)__expf(xx);
    }
    *(half4*)(P + (size_t)q * N_NODES + j) = pv;
}

// ---------------- k_main: DMA-staged masked MFMA ----------------
// grid 2048: b -> rb = b>>5 (64-row block), s = b&31 (128-col chunk). 4 waves, wave w = rows rb*64+w*16..+16.
// All global->LDS traffic via global_load_lds (zero VGPR, deep queue). One barrier. No cross-wave reduce.
__global__ __launch_bounds__(256, 3) void k_main(const int* __restrict__ adj,
                                                 const _Float16* __restrict__ P,
                                                 const _Float16* __restrict__ hT,
                                                 float* __restrict__ out_part,
                                                 float* __restrict__ den_part) {
    __shared__ int      lds_adj[4][8][256];   // [wave][c*2+half][1KB of ints]   32 KB
    __shared__ _Float16 lds_B[16][512];       // [g4*4+c][1KB of halfs]          16 KB
    __shared__ _Float16 lds_P[512];           // cols s*128.. (first 128 used)    1 KB

    int tid  = threadIdx.x;
    int lane = tid & 63;
    int w    = tid >> 6;
    int b    = blockIdx.x;
    int rb   = b >> 5;
    int s    = b & 31;
    int i0   = rb * 64 + w * 16;
    int n    = lane & 15;
    int quad = lane >> 4;

    // ---- issue all DMAs back-to-back ----
    // adj: wave-private rows. instr ch=c*2+half: lane reads 16B at row i0+n, col s*128+quad*8+c*32+half*4
    const int* adj_base = adj + (size_t)(i0 + n) * N_NODES + s * 128 + quad * 8;
#pragma unroll
    for (int c = 0; c < 4; ++c) {
        async_copy16(&lds_adj[w][c * 2 + 0][0], adj_base + c * 32);
        async_copy16(&lds_adj[w][c * 2 + 1][0], adj_base + c * 32 + 4);
    }
    // B: wave w stages g4=w. instr c: lane reads hT[(w*16+n)][s*128 + c*32 + quad*8], 16B
    const _Float16* hT_base = hT + (size_t)(w * 16 + n) * N_NODES + s * 128 + quad * 8;
#pragma unroll
    for (int c = 0; c < 4; ++c)
        async_copy16(&lds_B[w * 4 + c][0], hT_base + c * 32);
    // P: wave 0 stages 1KB (first 256B used)
    if (w == 0)
        async_copy16(&lds_P[0], P + (size_t)rb * N_NODES + s * 128 + lane * 8);
    __syncthreads();   // drains vmcnt; all LDS tiles visible

    // ---- MFMA over 4 k-steps of 32 ----
    floatx4 acc[4] = {{0,0,0,0},{0,0,0,0},{0,0,0,0},{0,0,0,0}};
    floatx4 accd = {0, 0, 0, 0};
    _Float16 one_h = (n == 0) ? (_Float16)1.0f : (_Float16)0.0f;
    half8 ones_f = {one_h, one_h, one_h, one_h, one_h, one_h, one_h, one_h};

#pragma unroll
    for (int c = 0; c < 4; ++c) {
        int4 ga = *(const int4*)&lds_adj[w][c * 2 + 0][lane * 4];
        int4 gb = *(const int4*)&lds_adj[w][c * 2 + 1][lane * 4];
        H8U4 pv, af;
        pv.h = *(const half8*)&lds_P[c * 32 + quad * 8];
        af.u[0] = pv.u[0] & ((ga.x > 0 ? 0x0000FFFFu : 0u) | (ga.y > 0 ? 0xFFFF0000u : 0u));
        af.u[1] = pv.u[1] & ((ga.z > 0 ? 0x0000FFFFu : 0u) | (ga.w > 0 ? 0xFFFF0000u : 0u));
        af.u[2] = pv.u[2] & ((gb.x > 0 ? 0x0000FFFFu : 0u) | (gb.y > 0 ? 0xFFFF0000u : 0u));
        af.u[3] = pv.u[3] & ((gb.z > 0 ? 0x0000FFFFu : 0u) | (gb.w > 0 ? 0xFFFF0000u : 0u));
#pragma unroll
        for (int g4 = 0; g4 < 4; ++g4) {
            half8 bf = *(const half8*)&lds_B[g4 * 4 + c][lane * 8];
            acc[g4] = __builtin_amdgcn_mfma_f32_16x16x32_f16(af.h, bf, acc[g4], 0, 0, 0);
        }
        accd = __builtin_amdgcn_mfma_f32_16x16x32_f16(af.h, ones_f, accd, 0, 0, 0);
    }

    // ---- store this chunk's private partial (C: row = quad*4+r, col = g4*16+n) ----
    float* op = out_part + ((size_t)s * N_NODES + i0) * F_OUT;
#pragma unroll
    for (int g4 = 0; g4 < 4; ++g4)
#pragma unroll
        for (int r = 0; r < 4; ++r)
            op[(quad * 4 + r) * F_OUT + g4 * 16 + n] = acc[g4][r];
    if (n == 0) {
#pragma unroll
        for (int r = 0; r < 4; ++r)
            den_part[s * N_NODES + i0 + quad * 4 + r] = accd[r];
    }
}

// ---------------- k_out: out = relu(sum_s out_part / sum_s den_part) + bias (float4) ----------------
__global__ __launch_bounds__(256) void k_out(const float* __restrict__ out_part,
                                             const float* __restrict__ den_part,
                                             const float* __restrict__ bias,
                                             float* __restrict__ out) {
    int idx4 = blockIdx.x * 256 + threadIdx.x;   // 65536 float4s
    int base = idx4 * 4;
    int i = base >> 6;
    int t = base & 63;
    float4 sacc = {0.f, 0.f, 0.f, 0.f};
    float dacc = 0.f;
#pragma unroll
    for (int p = 0; p < NPART; ++p) {
        float4 v = ((const float4*)(out_part + (size_t)p * N_NODES * F_OUT))[idx4];
        sacc.x += v.x; sacc.y += v.y; sacc.z += v.z; sacc.w += v.w;
        dacc += den_part[p * N_NODES + i];
    }
    float4 bv = *(const float4*)(bias + t);
    float4 o;
    o.x = fmaxf(sacc.x / dacc, 0.f) + bv.x;
    o.y = fmaxf(sacc.y / dacc, 0.f) + bv.y;
    o.z = fmaxf(sacc.z / dacc, 0.f) + bv.z;
    o.w = fmaxf(sacc.w / dacc, 0.f) + bv.w;
    ((float4*)out)[idx4] = o;
}

extern "C" void kernel_launch(void* const* d_in, const int* in_sizes, int n_in,
                              void* d_out, int out_size, void* d_ws, size_t ws_size,
                              hipStream_t stream) {
    const float* x    = (const float*)d_in[0];
    const int*   adj  = (const int*)d_in[1];
    const float* W    = (const float*)d_in[2];
    const float* a    = (const float*)d_in[3];
    const float* bias = (const float*)d_in[4];
    float* out = (float*)d_out;

    char* ws = (char*)d_ws;
    float*    h        = (float*)ws;                            // 1 MB
    _Float16* hT       = (_Float16*)(ws + 1024 * 1024);         // 512 KB
    float*    e1       = (float*)(ws + 1536 * 1024);            // 16 KB
    _Float16* P        = (_Float16*)(ws + 1552 * 1024);         // 512 KB
    _Float16* WT       = (_Float16*)(ws + 2064 * 1024);         // 64 KB
    float*    out_part = (float*)(ws + 2128 * 1024);            // 32 MB
    float*    den_part = (float*)(ws + (2128 + 32768) * 1024);  // 512 KB

    k_prep<<<128, 256, 0, stream>>>(W, WT);
    k_hW  <<<256, 256, 0, stream>>>(x, WT, a, h, hT, e1);
    k_TqP <<<256, 256, 0, stream>>>(h, a, e1, P);
    k_main<<<2048, 256, 0, stream>>>(adj, P, hT, out_part, den_part);
    k_out <<<256, 256, 0, stream>>>(out_part, den_part, bias, out);
}

// Round 12
// 126.036 us; speedup vs baseline: 1.2041x; 1.0205x over previous
//
#include <hip/hip_runtime.h>
#include <math.h>

#define N_NODES 4096
#define F_IN    512
#define F_OUT   64
#define ALPHA   0.2f
#define NPART   16

typedef _Float16 half8 __attribute__((ext_vector_type(8)));
typedef _Float16 half4 __attribute__((ext_vector_type(4)));
typedef float    floatx4 __attribute__((ext_vector_type(4)));

union H8U4 { half8 h; uint32_t u[4]; };

// async global->LDS DMA, 16B per lane, dest = lds_base + lane*16 (wave-uniform base)
__device__ __forceinline__ void async_copy16(void* lds, const void* g) {
    __builtin_amdgcn_global_load_lds(
        (const __attribute__((address_space(1))) unsigned int*)g,
        (__attribute__((address_space(3))) unsigned int*)lds, 16, 0, 0);
}

// ---------------- k_prep: WT[t][k] = f16(W[k][t])  (64 x 512) ----------------
__global__ __launch_bounds__(256) void k_prep(const float* __restrict__ W,
                                              _Float16* __restrict__ WT) {
    int idx = blockIdx.x * 256 + threadIdx.x;   // 32768 total
    int t = idx >> 9;
    int k = idx & 511;
    WT[idx] = (_Float16)W[k * F_OUT + t];
}

// ---------------- k_hW: h = x@W via MFMA (K-split across 4 waves); h, hT(f16), e1 ----------------
__global__ __launch_bounds__(256) void k_hW(const float* __restrict__ x,
                                            const _Float16* __restrict__ WT,
                                            const float* __restrict__ a,
                                            float* __restrict__ h,
                                            _Float16* __restrict__ hT,
                                            float* __restrict__ e1) {
    __shared__ float red[4][16][64];   // [wave][g4*4+r][lane]
    int tid  = threadIdx.x;
    int lane = tid & 63;
    int w    = tid >> 6;
    int i0   = blockIdx.x * 16;
    int n    = lane & 15;
    int quad = lane >> 4;

    floatx4 acc[4] = {{0,0,0,0},{0,0,0,0},{0,0,0,0},{0,0,0,0}};

    const float* xr = x + (size_t)(i0 + n) * F_IN + w * 128 + quad * 8;
    const _Float16* wb = WT + w * 128 + quad * 8;
#pragma unroll
    for (int kk = 0; kk < 128; kk += 32) {
        float4 x0 = *(const float4*)(xr + kk);
        float4 x1 = *(const float4*)(xr + kk + 4);
        half8 af = {(_Float16)x0.x, (_Float16)x0.y, (_Float16)x0.z, (_Float16)x0.w,
                    (_Float16)x1.x, (_Float16)x1.y, (_Float16)x1.z, (_Float16)x1.w};
#pragma unroll
        for (int g = 0; g < 4; ++g) {
            half8 bf = *(const half8*)(wb + (size_t)(g * 16 + n) * F_IN + kk);
            acc[g] = __builtin_amdgcn_mfma_f32_16x16x32_f16(af, bf, acc[g], 0, 0, 0);
        }
    }
#pragma unroll
    for (int g = 0; g < 4; ++g)
#pragma unroll
        for (int r = 0; r < 4; ++r)
            red[w][g * 4 + r][lane] = acc[g][r];
    __syncthreads();
    if (w != 0) return;
#pragma unroll
    for (int g = 0; g < 4; ++g)
#pragma unroll
        for (int r = 0; r < 4; ++r)
            acc[g][r] = red[0][g * 4 + r][lane] + red[1][g * 4 + r][lane] +
                        red[2][g * 4 + r][lane] + red[3][g * 4 + r][lane];
#pragma unroll
    for (int g = 0; g < 4; ++g) {
        half4 hv;
#pragma unroll
        for (int r = 0; r < 4; ++r) {
            h[(size_t)(i0 + quad * 4 + r) * F_OUT + g * 16 + n] = acc[g][r];
            hv[r] = (_Float16)acc[g][r];
        }
        *(half4*)(hT + (size_t)(g * 16 + n) * N_NODES + i0 + quad * 4) = hv;
    }
    float a1v[4];
#pragma unroll
    for (int g = 0; g < 4; ++g) a1v[g] = a[g * 16 + n];
#pragma unroll
    for (int r = 0; r < 4; ++r) {
        float v = acc[0][r] * a1v[0] + acc[1][r] * a1v[1] + acc[2][r] * a1v[2] + acc[3][r] * a1v[3];
        v += __shfl_xor(v, 1, 64);
        v += __shfl_xor(v, 2, 64);
        v += __shfl_xor(v, 4, 64);
        v += __shfl_xor(v, 8, 64);
        if (n == 0) e1[i0 + quad * 4 + r] = v;
    }
}

// ---------------- k_TqP: 256 blocks: block = (q, j-quarter). Tq in LDS, P slice ----------------
__global__ __launch_bounds__(256) void k_TqP(const float* __restrict__ h,
                                             const float* __restrict__ a,
                                             const float* __restrict__ e1,
                                             _Float16* __restrict__ P) {
    __shared__ float part[4][64];
    __shared__ float TqS[64];
    int b = blockIdx.x;
    int q = b >> 2;
    int quarter = b & 3;
    int tid = threadIdx.x;
    int t = tid & 63;
    int rp = tid >> 6;
    const float* a2 = a + F_OUT;
    float s = 0.f;
#pragma unroll
    for (int rr = 0; rr < 16; ++rr) {
        int r = rp * 16 + rr;
        s += a2[r] * h[(size_t)(r * 64 + q) * F_OUT + t];
    }
    part[rp][t] = s;
    __syncthreads();
    if (tid < 64) TqS[tid] = part[0][tid] + part[1][tid] + part[2][tid] + part[3][tid];
    __syncthreads();
    int j = quarter * 1024 + tid * 4;
    float4 ev = *(const float4*)(e1 + j);
    float4 tv = *(const float4*)(TqS + (j & 63));
    float e[4] = {ev.x + tv.x, ev.y + tv.y, ev.z + tv.z, ev.w + tv.w};
    half4 pv;
#pragma unroll
    for (int r = 0; r < 4; ++r) {
        float xx = e[r] > 0.f ? e[r] : ALPHA * e[r];
        pv[r] = (_Float16)__expf(xx);
    }
    *(half4*)(P + (size_t)q * N_NODES + j) = pv;
}

// ---------------- k_main: DMA-staged masked MFMA, 2-chunk K-loop (acc carried) ----------------
// grid 1024: b -> rb = b>>4 (64-row block), s = b&15 (256-col superchunk of 2x128).
// wave w = rows rb*64+w*16..+16. All global->LDS via global_load_lds. 2 barriers per chunk.
__global__ __launch_bounds__(256, 3) void k_main(const int* __restrict__ adj,
                                                 const _Float16* __restrict__ P,
                                                 const _Float16* __restrict__ hT,
                                                 float* __restrict__ out_part,
                                                 float* __restrict__ den_part) {
    __shared__ int      lds_adj[4][8][256];   // [wave][c*2+half][1KB of ints]   32 KB
    __shared__ _Float16 lds_B[16][512];       // [g4*4+c][1KB of halfs]          16 KB
    __shared__ _Float16 lds_P[512];           // 256 cols used (+256 DMA overrun) 1 KB

    int tid  = threadIdx.x;
    int lane = tid & 63;
    int w    = tid >> 6;
    int b    = blockIdx.x;
    int rb   = b >> 4;
    int s    = b & 15;
    int i0   = rb * 64 + w * 16;
    int n    = lane & 15;
    int quad = lane >> 4;

    // stage P slice for the whole superchunk once (512B used, 1KB written)
    if (w == 0)
        async_copy16(&lds_P[0], P + (size_t)rb * N_NODES + s * 256 + lane * 8);

    floatx4 acc[4] = {{0,0,0,0},{0,0,0,0},{0,0,0,0},{0,0,0,0}};
    floatx4 accd = {0, 0, 0, 0};
    _Float16 one_h = (n == 0) ? (_Float16)1.0f : (_Float16)0.0f;
    half8 ones_f = {one_h, one_h, one_h, one_h, one_h, one_h, one_h, one_h};

    for (int it = 0; it < 2; ++it) {
        int jb = s * 256 + it * 128;
        // ---- DMA this chunk: adj (wave-private rows) + B (wave w stages g4=w) ----
        const int* adj_base = adj + (size_t)(i0 + n) * N_NODES + jb + quad * 8;
#pragma unroll
        for (int c = 0; c < 4; ++c) {
            async_copy16(&lds_adj[w][c * 2 + 0][0], adj_base + c * 32);
            async_copy16(&lds_adj[w][c * 2 + 1][0], adj_base + c * 32 + 4);
        }
        const _Float16* hT_base = hT + (size_t)(w * 16 + n) * N_NODES + jb + quad * 8;
#pragma unroll
        for (int c = 0; c < 4; ++c)
            async_copy16(&lds_B[w * 4 + c][0], hT_base + c * 32);
        __syncthreads();   // drains vmcnt; tiles visible

        // ---- MFMA over 4 k-steps of 32 ----
#pragma unroll
        for (int c = 0; c < 4; ++c) {
            int4 ga = *(const int4*)&lds_adj[w][c * 2 + 0][lane * 4];
            int4 gb = *(const int4*)&lds_adj[w][c * 2 + 1][lane * 4];
            H8U4 pv, af;
            pv.h = *(const half8*)&lds_P[it * 128 + c * 32 + quad * 8];
            af.u[0] = pv.u[0] & ((ga.x > 0 ? 0x0000FFFFu : 0u) | (ga.y > 0 ? 0xFFFF0000u : 0u));
            af.u[1] = pv.u[1] & ((ga.z > 0 ? 0x0000FFFFu : 0u) | (ga.w > 0 ? 0xFFFF0000u : 0u));
            af.u[2] = pv.u[2] & ((gb.x > 0 ? 0x0000FFFFu : 0u) | (gb.y > 0 ? 0xFFFF0000u : 0u));
            af.u[3] = pv.u[3] & ((gb.z > 0 ? 0x0000FFFFu : 0u) | (gb.w > 0 ? 0xFFFF0000u : 0u));
#pragma unroll
            for (int g4 = 0; g4 < 4; ++g4) {
                half8 bf = *(const half8*)&lds_B[g4 * 4 + c][lane * 8];
                acc[g4] = __builtin_amdgcn_mfma_f32_16x16x32_f16(af.h, bf, acc[g4], 0, 0, 0);
            }
            accd = __builtin_amdgcn_mfma_f32_16x16x32_f16(af.h, ones_f, accd, 0, 0, 0);
        }
        __syncthreads();   // protect LDS before next chunk's DMA
    }

    // ---- store this superchunk's private partial (C: row = quad*4+r, col = g4*16+n) ----
    float* op = out_part + ((size_t)s * N_NODES + i0) * F_OUT;
#pragma unroll
    for (int g4 = 0; g4 < 4; ++g4)
#pragma unroll
        for (int r = 0; r < 4; ++r)
            op[(quad * 4 + r) * F_OUT + g4 * 16 + n] = acc[g4][r];
    if (n == 0) {
#pragma unroll
        for (int r = 0; r < 4; ++r)
            den_part[s * N_NODES + i0 + quad * 4 + r] = accd[r];
    }
}

// ---------------- k_out: out = relu(sum_s out_part / sum_s den_part) + bias (float4) ----------------
__global__ __launch_bounds__(128) void k_out(const float* __restrict__ out_part,
                                             const float* __restrict__ den_part,
                                             const float* __restrict__ bias,
                                             float* __restrict__ out) {
    int idx4 = blockIdx.x * 128 + threadIdx.x;   // 65536 float4s
    int base = idx4 * 4;
    int i = base >> 6;
    int t = base & 63;
    float4 sacc = {0.f, 0.f, 0.f, 0.f};
    float dacc = 0.f;
#pragma unroll
    for (int p = 0; p < NPART; ++p) {
        float4 v = ((const float4*)(out_part + (size_t)p * N_NODES * F_OUT))[idx4];
        sacc.x += v.x; sacc.y += v.y; sacc.z += v.z; sacc.w += v.w;
        dacc += den_part[p * N_NODES + i];
    }
    float4 bv = *(const float4*)(bias + t);
    float4 o;
    o.x = fmaxf(sacc.x / dacc, 0.f) + bv.x;
    o.y = fmaxf(sacc.y / dacc, 0.f) + bv.y;
    o.z = fmaxf(sacc.z / dacc, 0.f) + bv.z;
    o.w = fmaxf(sacc.w / dacc, 0.f) + bv.w;
    ((float4*)out)[idx4] = o;
}

extern "C" void kernel_launch(void* const* d_in, const int* in_sizes, int n_in,
                              void* d_out, int out_size, void* d_ws, size_t ws_size,
                              hipStream_t stream) {
    const float* x    = (const float*)d_in[0];
    const int*   adj  = (const int*)d_in[1];
    const float* W    = (const float*)d_in[2];
    const float* a    = (const float*)d_in[3];
    const float* bias = (const float*)d_in[4];
    float* out = (float*)d_out;

    char* ws = (char*)d_ws;
    float*    h        = (float*)ws;                            // 1 MB
    _Float16* hT       = (_Float16*)(ws + 1024 * 1024);         // 512 KB
    float*    e1       = (float*)(ws + 1536 * 1024);            // 16 KB
    _Float16* P        = (_Float16*)(ws + 1552 * 1024);         // 512 KB
    _Float16* WT       = (_Float16*)(ws + 2064 * 1024);         // 64 KB
    float*    out_part = (float*)(ws + 2128 * 1024);            // 16 MB
    float*    den_part = (float*)(ws + (2128 + 16384) * 1024);  // 256 KB

    k_prep<<<128, 256, 0, stream>>>(W, WT);
    k_hW  <<<256, 256, 0, stream>>>(x, WT, a, h, hT, e1);
    k_TqP <<<256, 256, 0, stream>>>(h, a, e1, P);
    k_main<<<1024, 256, 0, stream>>>(adj, P, hT, out_part, den_part);
    k_out <<<512, 128, 0, stream>>>(out_part, den_part, bias, out);
}

// Round 14
// 121.637 us; speedup vs baseline: 1.2477x; 1.0362x over previous
//
#include <hip/hip_runtime.h>
#include <math.h>

#define N_NODES 4096
#define F_IN    512
#define F_OUT   64
#define ALPHA   0.2f
#define NPART   8

typedef _Float16 half8 __attribute__((ext_vector_type(8)));
typedef _Float16 half4 __attribute__((ext_vector_type(4)));
typedef float    floatx4 __attribute__((ext_vector_type(4)));

union H8U4 { half8 h; uint32_t u[4]; };

// async global->LDS DMA, 16B per lane, dest = lds_base + lane*16 (wave-uniform base)
__device__ __forceinline__ void async_copy16(void* lds, const void* g) {
    __builtin_amdgcn_global_load_lds(
        (const __attribute__((address_space(1))) unsigned int*)g,
        (__attribute__((address_space(3))) unsigned int*)lds, 16, 0, 0);
}

// ---------------- k_prep: WT[t][k] = f16(W[k][t])  (64 x 512) ----------------
__global__ __launch_bounds__(256) void k_prep(const float* __restrict__ W,
                                              _Float16* __restrict__ WT) {
    int idx = blockIdx.x * 256 + threadIdx.x;   // 32768 total
    int t = idx >> 9;
    int k = idx & 511;
    WT[idx] = (_Float16)W[k * F_OUT + t];
}

// ---------------- k_hW: h = x@W via MFMA (K-split across 4 waves); h, hT(f16), e1 ----------------
__global__ __launch_bounds__(256) void k_hW(const float* __restrict__ x,
                                            const _Float16* __restrict__ WT,
                                            const float* __restrict__ a,
                                            float* __restrict__ h,
                                            _Float16* __restrict__ hT,
                                            float* __restrict__ e1) {
    __shared__ float red[4][16][64];   // [wave][g4*4+r][lane]
    int tid  = threadIdx.x;
    int lane = tid & 63;
    int w    = tid >> 6;
    int i0   = blockIdx.x * 16;
    int n    = lane & 15;
    int quad = lane >> 4;

    floatx4 acc[4] = {{0,0,0,0},{0,0,0,0},{0,0,0,0},{0,0,0,0}};

    const float* xr = x + (size_t)(i0 + n) * F_IN + w * 128 + quad * 8;
    const _Float16* wb = WT + w * 128 + quad * 8;
#pragma unroll
    for (int kk = 0; kk < 128; kk += 32) {
        float4 x0 = *(const float4*)(xr + kk);
        float4 x1 = *(const float4*)(xr + kk + 4);
        half8 af = {(_Float16)x0.x, (_Float16)x0.y, (_Float16)x0.z, (_Float16)x0.w,
                    (_Float16)x1.x, (_Float16)x1.y, (_Float16)x1.z, (_Float16)x1.w};
#pragma unroll
        for (int g = 0; g < 4; ++g) {
            half8 bf = *(const half8*)(wb + (size_t)(g * 16 + n) * F_IN + kk);
            acc[g] = __builtin_amdgcn_mfma_f32_16x16x32_f16(af, bf, acc[g], 0, 0, 0);
        }
    }
#pragma unroll
    for (int g = 0; g < 4; ++g)
#pragma unroll
        for (int r = 0; r < 4; ++r)
            red[w][g * 4 + r][lane] = acc[g][r];
    __syncthreads();
    if (w != 0) return;
#pragma unroll
    for (int g = 0; g < 4; ++g)
#pragma unroll
        for (int r = 0; r < 4; ++r)
            acc[g][r] = red[0][g * 4 + r][lane] + red[1][g * 4 + r][lane] +
                        red[2][g * 4 + r][lane] + red[3][g * 4 + r][lane];
#pragma unroll
    for (int g = 0; g < 4; ++g) {
        half4 hv;
#pragma unroll
        for (int r = 0; r < 4; ++r) {
            h[(size_t)(i0 + quad * 4 + r) * F_OUT + g * 16 + n] = acc[g][r];
            hv[r] = (_Float16)acc[g][r];
        }
        *(half4*)(hT + (size_t)(g * 16 + n) * N_NODES + i0 + quad * 4) = hv;
    }
    float a1v[4];
#pragma unroll
    for (int g = 0; g < 4; ++g) a1v[g] = a[g * 16 + n];
#pragma unroll
    for (int r = 0; r < 4; ++r) {
        float v = acc[0][r] * a1v[0] + acc[1][r] * a1v[1] + acc[2][r] * a1v[2] + acc[3][r] * a1v[3];
        v += __shfl_xor(v, 1, 64);
        v += __shfl_xor(v, 2, 64);
        v += __shfl_xor(v, 4, 64);
        v += __shfl_xor(v, 8, 64);
        if (n == 0) e1[i0 + quad * 4 + r] = v;
    }
}

// ---------------- k_TqP: 256 blocks: block = (q, j-quarter). Tq in LDS, P slice ----------------
__global__ __launch_bounds__(256) void k_TqP(const float* __restrict__ h,
                                             const float* __restrict__ a,
                                             const float* __restrict__ e1,
                                             _Float16* __restrict__ P) {
    __shared__ float part[4][64];
    __shared__ float TqS[64];
    int b = blockIdx.x;
    int q = b >> 2;
    int quarter = b & 3;
    int tid = threadIdx.x;
    int t = tid & 63;
    int rp = tid >> 6;
    const float* a2 = a + F_OUT;
    float s = 0.f;
#pragma unroll
    for (int rr = 0; rr < 16; ++rr) {
        int r = rp * 16 + rr;
        s += a2[r] * h[(size_t)(r * 64 + q) * F_OUT + t];
    }
    part[rp][t] = s;
    __syncthreads();
    if (tid < 64) TqS[tid] = part[0][tid] + part[1][tid] + part[2][tid] + part[3][tid];
    __syncthreads();
    int j = quarter * 1024 + tid * 4;
    float4 ev = *(const float4*)(e1 + j);
    float4 tv = *(const float4*)(TqS + (j & 63));
    float e[4] = {ev.x + tv.x, ev.y + tv.y, ev.z + tv.z, ev.w + tv.w};
    half4 pv;
#pragma unroll
    for (int r = 0; r < 4; ++r) {
        float xx = e[r] > 0.f ? e[r] : ALPHA * e[r];
        pv[r] = (_Float16)__expf(xx);
    }
    *(half4*)(P + (size_t)q * N_NODES + j) = pv;
}

// ---------------- k_main: DMA-staged masked MFMA, 4-chunk K-loop (acc carried) ----------------
// grid 512: b -> rb = b>>3 (64-row block), s = b&7 (512-col superchunk = 4x128).
// wave w = rows rb*64+w*16..+16. All global->LDS via global_load_lds. 2 barriers per chunk.
__global__ __launch_bounds__(256, 3) void k_main(const int* __restrict__ adj,
                                                 const _Float16* __restrict__ P,
                                                 const _Float16* __restrict__ hT,
                                                 float* __restrict__ out_part,
                                                 float* __restrict__ den_part) {
    __shared__ int      lds_adj[4][8][256];   // [wave][c*2+half][1KB of ints]   32 KB
    __shared__ _Float16 lds_B[16][512];       // [g4*4+c][1KB of halfs]          16 KB
    __shared__ _Float16 lds_P[512];           // cols s*512 .. +512               1 KB

    int tid  = threadIdx.x;
    int lane = tid & 63;
    int w    = tid >> 6;
    int b    = blockIdx.x;
    int rb   = b >> 3;
    int s    = b & 7;
    int i0   = rb * 64 + w * 16;
    int n    = lane & 15;
    int quad = lane >> 4;

    // stage P slice for the whole superchunk once (512 halfs = 1 KB, one DMA)
    if (w == 0)
        async_copy16(&lds_P[0], P + (size_t)rb * N_NODES + s * 512 + lane * 8);

    floatx4 acc[4] = {{0,0,0,0},{0,0,0,0},{0,0,0,0},{0,0,0,0}};
    floatx4 accd = {0, 0, 0, 0};
    _Float16 one_h = (n == 0) ? (_Float16)1.0f : (_Float16)0.0f;
    half8 ones_f = {one_h, one_h, one_h, one_h, one_h, one_h, one_h, one_h};

    for (int it = 0; it < 4; ++it) {
        int jb = s * 512 + it * 128;
        // ---- DMA this chunk: adj (wave-private rows) + B (wave w stages g4=w) ----
        const int* adj_base = adj + (size_t)(i0 + n) * N_NODES + jb + quad * 8;
#pragma unroll
        for (int c = 0; c < 4; ++c) {
            async_copy16(&lds_adj[w][c * 2 + 0][0], adj_base + c * 32);
            async_copy16(&lds_adj[w][c * 2 + 1][0], adj_base + c * 32 + 4);
        }
        const _Float16* hT_base = hT + (size_t)(w * 16 + n) * N_NODES + jb + quad * 8;
#pragma unroll
        for (int c = 0; c < 4; ++c)
            async_copy16(&lds_B[w * 4 + c][0], hT_base + c * 32);
        __syncthreads();   // drains vmcnt; tiles visible

        // ---- MFMA over 4 k-steps of 32 ----
#pragma unroll
        for (int c = 0; c < 4; ++c) {
            int4 ga = *(const int4*)&lds_adj[w][c * 2 + 0][lane * 4];
            int4 gb = *(const int4*)&lds_adj[w][c * 2 + 1][lane * 4];
            H8U4 pv, af;
            pv.h = *(const half8*)&lds_P[it * 128 + c * 32 + quad * 8];
            af.u[0] = pv.u[0] & ((ga.x > 0 ? 0x0000FFFFu : 0u) | (ga.y > 0 ? 0xFFFF0000u : 0u));
            af.u[1] = pv.u[1] & ((ga.z > 0 ? 0x0000FFFFu : 0u) | (ga.w > 0 ? 0xFFFF0000u : 0u));
            af.u[2] = pv.u[2] & ((gb.x > 0 ? 0x0000FFFFu : 0u) | (gb.y > 0 ? 0xFFFF0000u : 0u));
            af.u[3] = pv.u[3] & ((gb.z > 0 ? 0x0000FFFFu : 0u) | (gb.w > 0 ? 0xFFFF0000u : 0u));
#pragma unroll
            for (int g4 = 0; g4 < 4; ++g4) {
                half8 bf = *(const half8*)&lds_B[g4 * 4 + c][lane * 8];
                acc[g4] = __builtin_amdgcn_mfma_f32_16x16x32_f16(af.h, bf, acc[g4], 0, 0, 0);
            }
            accd = __builtin_amdgcn_mfma_f32_16x16x32_f16(af.h, ones_f, accd, 0, 0, 0);
        }
        __syncthreads();   // protect LDS before next chunk's DMA
    }

    // ---- store this superchunk's private partial (C: row = quad*4+r, col = g4*16+n) ----
    float* op = out_part + ((size_t)s * N_NODES + i0) * F_OUT;
#pragma unroll
    for (int g4 = 0; g4 < 4; ++g4)
#pragma unroll
        for (int r = 0; r < 4; ++r)
            op[(quad * 4 + r) * F_OUT + g4 * 16 + n] = acc[g4][r];
    if (n == 0) {
#pragma unroll
        for (int r = 0; r < 4; ++r)
            den_part[s * N_NODES + i0 + quad * 4 + r] = accd[r];
    }
}

// ---------------- k_out: out = relu(sum_s out_part / sum_s den_part) + bias (float4) ----------------
__global__ __launch_bounds__(128) void k_out(const float* __restrict__ out_part,
                                             const float* __restrict__ den_part,
                                             const float* __restrict__ bias,
                                             float* __restrict__ out) {
    int idx4 = blockIdx.x * 128 + threadIdx.x;   // 65536 float4s
    int base = idx4 * 4;
    int i = base >> 6;
    int t = base & 63;
    float4 sacc = {0.f, 0.f, 0.f, 0.f};
    float dacc = 0.f;
#pragma unroll
    for (int p = 0; p < NPART; ++p) {
        float4 v = ((const float4*)(out_part + (size_t)p * N_NODES * F_OUT))[idx4];
        sacc.x += v.x; sacc.y += v.y; sacc.z += v.z; sacc.w += v.w;
        dacc += den_part[p * N_NODES + i];
    }
    float4 bv = *(const float4*)(bias + t);
    float4 o;
    o.x = fmaxf(sacc.x / dacc, 0.f) + bv.x;
    o.y = fmaxf(sacc.y / dacc, 0.f) + bv.y;
    o.z = fmaxf(sacc.z / dacc, 0.f) + bv.z;
    o.w = fmaxf(sacc.w / dacc, 0.f) + bv.w;
    ((float4*)out)[idx4] = o;
}

extern "C" void kernel_launch(void* const* d_in, const int* in_sizes, int n_in,
                              void* d_out, int out_size, void* d_ws, size_t ws_size,
                              hipStream_t stream) {
    const float* x    = (const float*)d_in[0];
    const int*   adj  = (const int*)d_in[1];
    const float* W    = (const float*)d_in[2];
    const float* a    = (const float*)d_in[3];
    const float* bias = (const float*)d_in[4];
    float* out = (float*)d_out;

    char* ws = (char*)d_ws;
    float*    h        = (float*)ws;                            // 1 MB
    _Float16* hT       = (_Float16*)(ws + 1024 * 1024);         // 512 KB
    float*    e1       = (float*)(ws + 1536 * 1024);            // 16 KB
    _Float16* P        = (_Float16*)(ws + 1552 * 1024);         // 512 KB
    _Float16* WT       = (_Float16*)(ws + 2064 * 1024);         // 64 KB
    float*    out_part = (float*)(ws + 2128 * 1024);            // 8 MB (NPART=8, fp32)
    float*    den_part = (float*)(ws + (2128 + 8192) * 1024);   // 128 KB

    k_prep<<<128, 256, 0, stream>>>(W, WT);
    k_hW  <<<256, 256, 0, stream>>>(x, WT, a, h, hT, e1);
    k_TqP <<<256, 256, 0, stream>>>(h, a, e1, P);
    k_main<<<512, 256, 0, stream>>>(adj, P, hT, out_part, den_part);
    k_out <<<512, 128, 0, stream>>>(out_part, den_part, bias, out);
}